// Round 10
// baseline (275.199 us; speedup 1.0000x reference)
//
#include <hip/hip_runtime.h>

// PointPillars voxelization, MI355X. Output FLOAT32 flat concat:
//   voxels [40000][32][8], coords [40000][3] (z,y,x), num_points [40000].
// Input float32 [N][8]. PASSED r6-r9 (absmax 0) with binning:
//   cx=floor(x*6.25f), cy=floor((y+39.68f)*6.25f), cz=floor((z+3.f)*0.25f)
// (XLA div-by-const -> mul-by-reciprocal, f32 RN). DO NOT CHANGE BINNING.
//
// r10: single fused kernel (memset node + 1 kernel node). Phases
// prep -> blocksum -> ranks -> append -> emit separated by a manual
// device-scope grid barrier (512 blocks co-resident by construction:
// launch_bounds(256,4) caps VGPR at 128 -> >=4 blocks/CU -> capacity 1024).
// r8/r9 calibration: ~30us of memory work + ~25us of per-node overhead,
// so fusing nodes is the remaining lever.

constexpr int NXv = 432;
constexpr int NYv = 496;
constexpr int NZv = 1;
constexpr int NVOX = NXv * NYv * NZv;      // 214272
constexpr int MAX_PTSv = 32;
constexpr int MAX_VOXv = 40000;
constexpr int SLOT_CAP = 64;               // 64 ints = 256B, row = 1024B
constexpr int SCAN_BS = 256;
constexpr int NBLK = NVOX / SCAN_BS;       // 837 exact
constexpr int GRID_B = 512;                // co-resident with 2x margin

constexpr size_t VOX_F   = (size_t)MAX_VOXv * MAX_PTSv * 8;  // 10,240,000 f32
constexpr size_t COORD_F = (size_t)MAX_VOXv * 3;             // 120,000 f32

__device__ __forceinline__ int voxel_id(float x, float y, float z) {
    float fx = x * 6.25f;
    float fy = (y + 39.68f) * 6.25f;
    float fz = (z + 3.0f) * 0.25f;
    int cx = (int)floorf(fx);
    int cy = (int)floorf(fy);
    int cz = (int)floorf(fz);
    if (cx < 0 || cx >= NXv || cy < 0 || cy >= NYv || cz < 0 || cz >= NZv)
        return -1;
    return (cz * NYv + cy) * NXv + cx;
}

// device-scope grid barrier; bar points at a pre-zeroed u32 (one per phase).
__device__ __forceinline__ void gbar(unsigned int* bar, unsigned int nblk) {
    __syncthreads();
    if (threadIdx.x == 0) {
        __threadfence();                       // release (L2 wb at agent scope)
        atomicAdd(bar, 1u);                    // device-scope arrive
        while (__hip_atomic_load(bar, __ATOMIC_RELAXED,
                                 __HIP_MEMORY_SCOPE_AGENT) < nblk)
            __builtin_amdgcn_s_sleep(2);
        __threadfence();                       // acquire (L1/L2 inv)
    }
    __syncthreads();
}

__global__ __launch_bounds__(256, 4)
void k_fused(const float* __restrict__ pf, int N,
             unsigned char* __restrict__ occ,
             unsigned int* __restrict__ appcnt,
             unsigned int* __restrict__ scal,
             unsigned int* __restrict__ bar,
             unsigned int* __restrict__ bsums,
             int* __restrict__ rank_of,
             int* __restrict__ vid_of_rank,
             int* __restrict__ vids,
             float* __restrict__ out) {
    const int G = gridDim.x;
    const int bid = blockIdx.x;
    const int t = threadIdx.x;

    __shared__ unsigned int sh[SCAN_BS];
    __shared__ unsigned int pr[SCAN_BS];
    __shared__ unsigned int wsum[SCAN_BS / 64];
    __shared__ int sidx[4][64];

    // ---- P1: per-point vid + occupancy (plain byte store) ----
    for (int i = bid * SCAN_BS + t; i < N; i += G * SCAN_BS) {
        float4 v = reinterpret_cast<const float4*>(pf)[(size_t)i * 2];
        int vid = voxel_id(v.x, v.y, v.z);
        vids[i] = vid;
        if (vid >= 0) occ[vid] = 1;
    }
    gbar(&bar[0], G);

    // ---- P2: per-256-chunk occupancy sums ----
    for (int vb = bid; vb < NBLK; vb += G) {
        int i = vb * SCAN_BS + t;
        int flag = (occ[i] != 0) ? 1 : 0;
        unsigned long long b = __ballot(flag);
        if ((t & 63) == 0) wsum[t >> 6] = (unsigned)__popcll(b);
        __syncthreads();
        if (t == 0) bsums[vb] = wsum[0] + wsum[1] + wsum[2] + wsum[3];
        __syncthreads();
    }
    gbar(&bar[1], G);

    // ---- P3: ranks (per-chunk: redundant prefix over bsums + local scan) ----
    for (int vb = bid; vb < NBLK; vb += G) {
        unsigned p = 0;
        for (int j = t; j < vb; j += SCAN_BS) p += bsums[j];
        pr[t] = p;
        __syncthreads();
        for (int off = SCAN_BS / 2; off >= 1; off >>= 1) {
            if (t < off) pr[t] += pr[t + off];
            __syncthreads();
        }
        unsigned excl = pr[0];

        int i = vb * SCAN_BS + t;
        int flag = (occ[i] != 0) ? 1 : 0;
        sh[t] = (unsigned)flag;
        __syncthreads();
        for (int off = 1; off < SCAN_BS; off <<= 1) {
            unsigned add = (t >= off) ? sh[t - off] : 0u;
            __syncthreads();
            sh[t] += add;
            __syncthreads();
        }
        unsigned rank = excl + sh[t] - (unsigned)flag;
        int r = (flag && rank < (unsigned)MAX_VOXv) ? (int)rank : -1;
        rank_of[i] = r;
        if (r >= 0) vid_of_rank[r] = i;
        if (vb == NBLK - 1 && t == SCAN_BS - 1) scal[0] = excl + sh[t];
        __syncthreads();                    // protect sh/pr for next iter
    }
    gbar(&bar[2], G);

    // ---- P4: append point indices into row heads ----
    for (int i = bid * SCAN_BS + t; i < N; i += G * SCAN_BS) {
        int vid = vids[i];
        if (vid < 0) continue;
        int r = rank_of[vid];
        if (r < 0) continue;
        unsigned s = atomicAdd(&appcnt[r], 1u);
        if (s < (unsigned)SLOT_CAP) {
            int* rowi = reinterpret_cast<int*>(out + (size_t)r * (MAX_PTSv * 8));
            rowi[s] = i;
        }
    }
    gbar(&bar[3], G);

    // ---- P5: emit (4 rows per block; 64 lanes per row) ----
    unsigned K = min(scal[0], (unsigned)MAX_VOXv);
    float* out_coord = out + VOX_F;
    float* out_num   = out + VOX_F + COORD_F;
    const int sub = t >> 6;
    const int lane = t & 63;
    for (int g = bid; g < MAX_VOXv / 4; g += G) {
        int r = g * 4 + sub;
        float* row = out + (size_t)r * (MAX_PTSv * 8);
        bool isocc = (unsigned)r < K;
        int c = 0;
        if (isocc) c = (int)min(appcnt[r], (unsigned)SLOT_CAP);
        const int* rowi = reinterpret_cast<const int*>(row);
        sidx[sub][lane] = (lane < c) ? rowi[lane] : 0x7fffffff;
        __syncthreads();                    // drains slot loads, LDS visible
        if (isocc) {
            int nkeep = c < MAX_PTSv ? c : MAX_PTSv;
            if (lane < c) {
                int my = sidx[sub][lane];
                int pos = 0;
                for (int j = 0; j < c; ++j) pos += (sidx[sub][j] < my) ? 1 : 0;
                if (pos < MAX_PTSv) {
                    const float4* src =
                        reinterpret_cast<const float4*>(pf) + (size_t)my * 2;
                    float4 a = src[0];
                    float4 b = src[1];
                    float4* dst = reinterpret_cast<float4*>(row + pos * 8);
                    dst[0] = a;
                    dst[1] = b;
                }
            }
            if (lane >= nkeep && lane < MAX_PTSv) {
                float4* dst = reinterpret_cast<float4*>(row + lane * 8);
                dst[0] = make_float4(0.f, 0.f, 0.f, 0.f);
                dst[1] = make_float4(0.f, 0.f, 0.f, 0.f);
            }
            if (lane == 0) {
                int vid = vid_of_rank[r];
                int vx = vid % NXv;
                int vy = (vid / NXv) % NYv;
                int vz = vid / (NXv * NYv);
                out_coord[(size_t)r * 3 + 0] = (float)vz;
                out_coord[(size_t)r * 3 + 1] = (float)vy;
                out_coord[(size_t)r * 3 + 2] = (float)vx;
                out_num[r] = (float)nkeep;
            }
        } else {
            reinterpret_cast<float4*>(row)[lane] = make_float4(0.f, 0.f, 0.f, 0.f);
            if (lane == 0) {
                out_coord[(size_t)r * 3 + 0] = 0.f;
                out_coord[(size_t)r * 3 + 1] = 0.f;
                out_coord[(size_t)r * 3 + 2] = 0.f;
                out_num[r] = 0.f;
            }
        }
        __syncthreads();                    // protect sidx for next iter
    }
}

// ---------- fallback path (r6 proven, 7 kernels) ----------

__global__ void k_zero(unsigned int* p, int n) {
    int i = blockIdx.x * blockDim.x + threadIdx.x;
    int stride = gridDim.x * blockDim.x;
    for (; i < n; i += stride) p[i] = 0u;
}

__global__ void k_count(const float* __restrict__ pf, int N,
                        unsigned int* __restrict__ counts) {
    int i = blockIdx.x * blockDim.x + threadIdx.x;
    if (i >= N) return;
    float4 v = reinterpret_cast<const float4*>(pf)[(size_t)i * 2];
    int vid = voxel_id(v.x, v.y, v.z);
    if (vid >= 0) atomicAdd(&counts[vid], 1u);
}

__global__ void k_blocksum(const unsigned int* __restrict__ counts,
                           unsigned int* __restrict__ bsums) {
    int i = blockIdx.x * SCAN_BS + threadIdx.x;
    int flag = (counts[i] != 0u) ? 1 : 0;
    unsigned long long b = __ballot(flag);
    __shared__ unsigned int wsum[SCAN_BS / 64];
    if ((threadIdx.x & 63) == 0) wsum[threadIdx.x >> 6] = (unsigned)__popcll(b);
    __syncthreads();
    if (threadIdx.x == 0) {
        unsigned s = 0;
        for (int w = 0; w < SCAN_BS / 64; ++w) s += wsum[w];
        bsums[blockIdx.x] = s;
    }
}

__global__ void k_scan_bsums(unsigned int* __restrict__ bsums,
                             unsigned int* __restrict__ scal) {
    __shared__ unsigned int sh[1024];
    int t = threadIdx.x;
    unsigned v = (t < NBLK) ? bsums[t] : 0u;
    sh[t] = v;
    __syncthreads();
    for (int off = 1; off < 1024; off <<= 1) {
        unsigned add = (t >= off) ? sh[t - off] : 0u;
        __syncthreads();
        sh[t] += add;
        __syncthreads();
    }
    if (t < NBLK) bsums[t] = sh[t] - v;
    if (t == NBLK - 1) scal[0] = sh[t];
}

__global__ void k_ranks(const unsigned int* __restrict__ counts,
                        const unsigned int* __restrict__ bsums,
                        int* __restrict__ rank_of, int* __restrict__ vid_of_rank) {
    int i = blockIdx.x * SCAN_BS + threadIdx.x;
    int t = threadIdx.x;
    int flag = (counts[i] != 0u) ? 1 : 0;
    __shared__ unsigned int sh[SCAN_BS];
    sh[t] = (unsigned)flag;
    __syncthreads();
    for (int off = 1; off < SCAN_BS; off <<= 1) {
        unsigned add = (t >= off) ? sh[t - off] : 0u;
        __syncthreads();
        sh[t] += add;
        __syncthreads();
    }
    unsigned rank = bsums[blockIdx.x] + sh[t] - (unsigned)flag;
    int r = (flag && rank < (unsigned)MAX_VOXv) ? (int)rank : -1;
    rank_of[i] = r;
    if (r >= 0) vid_of_rank[r] = i;
}

__global__ void k_append(const float* __restrict__ pf, int N,
                         const int* __restrict__ rank_of,
                         unsigned int* __restrict__ appcnt,
                         float* __restrict__ out) {
    int i = blockIdx.x * blockDim.x + threadIdx.x;
    if (i >= N) return;
    float4 v = reinterpret_cast<const float4*>(pf)[(size_t)i * 2];
    int vid = voxel_id(v.x, v.y, v.z);
    if (vid < 0) return;
    int r = rank_of[vid];
    if (r < 0) return;
    unsigned s = atomicAdd(&appcnt[r], 1u);
    if (s < (unsigned)SLOT_CAP) {
        int* rowi = reinterpret_cast<int*>(out + (size_t)r * (MAX_PTSv * 8));
        rowi[s] = i;
    }
}

__global__ void k_emit(const float* __restrict__ pf,
                       const unsigned int* __restrict__ appcnt,
                       const int* __restrict__ vid_of_rank,
                       const unsigned int* __restrict__ scal,
                       float* __restrict__ out) {
    int r = blockIdx.x;
    int t = threadIdx.x;
    float* row       = out + (size_t)r * (MAX_PTSv * 8);
    float* out_coord = out + VOX_F;
    float* out_num   = out + VOX_F + COORD_F;
    unsigned K = min(scal[0], (unsigned)MAX_VOXv);

    if ((unsigned)r >= K) {
        reinterpret_cast<float4*>(row)[t] = make_float4(0.f, 0.f, 0.f, 0.f);
        if (t == 0) {
            out_coord[(size_t)r * 3 + 0] = 0.f;
            out_coord[(size_t)r * 3 + 1] = 0.f;
            out_coord[(size_t)r * 3 + 2] = 0.f;
            out_num[r] = 0.f;
        }
        return;
    }

    __shared__ int sidx[SLOT_CAP];
    int c = (int)min(appcnt[r], (unsigned)SLOT_CAP);
    const int* rowi = reinterpret_cast<const int*>(row);
    sidx[t] = (t < c) ? rowi[t] : 0x7fffffff;
    __syncthreads();
    int nkeep = c < MAX_PTSv ? c : MAX_PTSv;

    if (t < c) {
        int my = sidx[t];
        int pos = 0;
        for (int j = 0; j < c; ++j) pos += (sidx[j] < my) ? 1 : 0;
        if (pos < MAX_PTSv) {
            const float4* src = reinterpret_cast<const float4*>(pf) + (size_t)my * 2;
            float4 a = src[0];
            float4 b = src[1];
            float4* dst = reinterpret_cast<float4*>(row + pos * 8);
            dst[0] = a;
            dst[1] = b;
        }
    }
    if (t >= nkeep && t < MAX_PTSv) {
        float4* dst = reinterpret_cast<float4*>(row + t * 8);
        dst[0] = make_float4(0.f, 0.f, 0.f, 0.f);
        dst[1] = make_float4(0.f, 0.f, 0.f, 0.f);
    }
    if (t == 0) {
        int vid = vid_of_rank[r];
        int vx = vid % NXv;
        int vy = (vid / NXv) % NYv;
        int vz = vid / (NXv * NYv);
        out_coord[(size_t)r * 3 + 0] = (float)vz;
        out_coord[(size_t)r * 3 + 1] = (float)vy;
        out_coord[(size_t)r * 3 + 2] = (float)vx;
        out_num[r] = (float)nkeep;
    }
}

extern "C" void kernel_launch(void* const* d_in, const int* in_sizes, int n_in,
                              void* d_out, int out_size, void* d_ws, size_t ws_size,
                              hipStream_t stream) {
    const float* pf = (const float*)d_in[0];
    const int N = in_sizes[0] / 8;
    float* out = (float*)d_out;

    // fused-path ws layout (bytes), zero-region first (memset node):
    //   [occ u8 215040][appcnt u32 160000][scal 64][bar 64]       = 375168
    //   [bsums 4096][rank_of i32 NVOX][vid_of_rank i32 MAX_VOX][vids i32 N]
    const size_t OCC_B  = 215040;
    const size_t APP_B  = (size_t)MAX_VOXv * 4;   // 160000
    const size_t SCAL_B = 64;
    const size_t BAR_B  = 64;
    const size_t ZERO_B = OCC_B + APP_B + SCAL_B + BAR_B;   // 375168
    const size_t BS_B   = 4096;
    const size_t RANK_B = (size_t)NVOX * 4;                 // 857088
    const size_t VOR_B  = (size_t)MAX_VOXv * 4;             // 160000
    const size_t NEED   = ZERO_B + BS_B + RANK_B + VOR_B + (size_t)N * 4;

    char* wsb = (char*)d_ws;
    unsigned char* occ        = (unsigned char*)wsb;
    unsigned int* appcnt      = (unsigned int*)(wsb + OCC_B);
    unsigned int* scal        = (unsigned int*)(wsb + OCC_B + APP_B);
    unsigned int* bar         = (unsigned int*)(wsb + OCC_B + APP_B + SCAL_B);
    unsigned int* bsums       = (unsigned int*)(wsb + ZERO_B);
    int*          rank_of     = (int*)(wsb + ZERO_B + BS_B);
    int*          vid_of_rank = (int*)(wsb + ZERO_B + BS_B + RANK_B);
    int*          vids        = (int*)(wsb + ZERO_B + BS_B + RANK_B + VOR_B);

    if (ws_size >= NEED) {
        hipMemsetAsync(d_ws, 0, ZERO_B, stream);
        k_fused<<<GRID_B, SCAN_BS, 0, stream>>>(pf, N, occ, appcnt, scal, bar,
                                                bsums, rank_of, vid_of_rank,
                                                vids, out);
        return;
    }

    // fallback: r6 proven layout/path (~2.04 MB)
    unsigned int* wsp          = (unsigned int*)d_ws;
    unsigned int* counts_f     = wsp;
    unsigned int* appcnt_f     = counts_f + NVOX;
    unsigned int* bsums_f      = appcnt_f + MAX_VOXv;
    unsigned int* scal_f       = bsums_f + 1024;
    int*          rank_of_f    = (int*)(scal_f + 4);
    int*          vid_of_rk_f  = rank_of_f + NVOX;

    const int n_zero = NVOX + MAX_VOXv + 1024 + 4;
    k_zero<<<512, 256, 0, stream>>>(wsp, n_zero);
    k_count<<<(N + 255) / 256, 256, 0, stream>>>(pf, N, counts_f);
    k_blocksum<<<NBLK, SCAN_BS, 0, stream>>>(counts_f, bsums_f);
    k_scan_bsums<<<1, 1024, 0, stream>>>(bsums_f, scal_f);
    k_ranks<<<NBLK, SCAN_BS, 0, stream>>>(counts_f, bsums_f, rank_of_f, vid_of_rk_f);
    k_append<<<(N + 255) / 256, 256, 0, stream>>>(pf, N, rank_of_f, appcnt_f, out);
    k_emit<<<MAX_VOXv, 64, 0, stream>>>(pf, appcnt_f, vid_of_rk_f, scal_f, out);
}

// Round 11
// 56.103 us; speedup vs baseline: 4.9052x; 4.9052x over previous
//
#include <hip/hip_runtime.h>

// PointPillars voxelization, MI355X. Output FLOAT32 flat concat:
//   voxels [40000][32][8], coords [40000][3] (z,y,x), num_points [40000].
// Input float32 [N][8]. PASSED r6-r10 (absmax 0) with binning:
//   cx=floor(x*6.25f), cy=floor((y+39.68f)*6.25f), cz=floor((z+3.f)*0.25f)
// (XLA div-by-const -> mul-by-reciprocal, f32 RN). DO NOT CHANGE BINNING.
//
// r11: multi-kernel (r10 proved grid barriers cost ~60us each on gfx950 --
// agent-scope fences force L2 wb/inv on non-coherent per-XCD L2s).
// Node-count reduction instead: memset node (DMA) replaces k_zero kernel;
// k_ranks3 folds the bsums prefix (r10-verified redundant-prefix) killing
// the serial 1-block scan node; emit processes 4 rows/block (r10-verified).
// Chain: memset -> prep -> blocksum -> ranks3 -> append -> emit (6 nodes).

constexpr int NXv = 432;
constexpr int NYv = 496;
constexpr int NZv = 1;
constexpr int NVOX = NXv * NYv * NZv;      // 214272
constexpr int MAX_PTSv = 32;
constexpr int MAX_VOXv = 40000;
constexpr int SLOT_CAP = 64;               // 64 ints = 256B, row = 1024B
constexpr int SCAN_BS = 256;
constexpr int NBLK = NVOX / SCAN_BS;       // 837 exact

constexpr size_t VOX_F   = (size_t)MAX_VOXv * MAX_PTSv * 8;  // 10,240,000 f32
constexpr size_t COORD_F = (size_t)MAX_VOXv * 3;             // 120,000 f32

__device__ __forceinline__ int voxel_id(float x, float y, float z) {
    float fx = x * 6.25f;
    float fy = (y + 39.68f) * 6.25f;
    float fz = (z + 3.0f) * 0.25f;
    int cx = (int)floorf(fx);
    int cy = (int)floorf(fy);
    int cz = (int)floorf(fz);
    if (cx < 0 || cx >= NXv || cy < 0 || cy >= NYv || cz < 0 || cz >= NZv)
        return -1;
    return (cz * NYv + cy) * NXv + cx;
}

// ---------- fast path ----------

__global__ void k_prep(const float* __restrict__ pf, int N,
                       int* __restrict__ vids, unsigned char* __restrict__ occ) {
    int i = blockIdx.x * blockDim.x + threadIdx.x;
    if (i >= N) return;
    float4 v = reinterpret_cast<const float4*>(pf)[(size_t)i * 2];
    int vid = voxel_id(v.x, v.y, v.z);
    vids[i] = vid;
    if (vid >= 0) occ[vid] = 1;          // plain byte store, no RMW
}

__global__ void k_blocksum2(const unsigned char* __restrict__ occ,
                            unsigned int* __restrict__ bsums) {
    int i = blockIdx.x * SCAN_BS + threadIdx.x;
    int flag = (occ[i] != 0) ? 1 : 0;
    unsigned long long b = __ballot(flag);
    __shared__ unsigned int wsum[SCAN_BS / 64];
    if ((threadIdx.x & 63) == 0) wsum[threadIdx.x >> 6] = (unsigned)__popcll(b);
    __syncthreads();
    if (threadIdx.x == 0) {
        unsigned s = 0;
        for (int w = 0; w < SCAN_BS / 64; ++w) s += wsum[w];
        bsums[blockIdx.x] = s;
    }
}

// ranks with in-kernel redundant prefix over bsums (r10-P3 verified)
__global__ void k_ranks3(const unsigned char* __restrict__ occ,
                         const unsigned int* __restrict__ bsums,
                         unsigned int* __restrict__ scal,
                         int* __restrict__ rank_of,
                         int* __restrict__ vid_of_rank) {
    const int vb = blockIdx.x;
    const int t = threadIdx.x;
    __shared__ unsigned int pr[SCAN_BS];
    __shared__ unsigned int sh[SCAN_BS];

    unsigned p = 0;
    for (int j = t; j < vb; j += SCAN_BS) p += bsums[j];
    pr[t] = p;
    __syncthreads();
    for (int off = SCAN_BS / 2; off >= 1; off >>= 1) {
        if (t < off) pr[t] += pr[t + off];
        __syncthreads();
    }
    unsigned excl = pr[0];

    int i = vb * SCAN_BS + t;
    int flag = (occ[i] != 0) ? 1 : 0;
    sh[t] = (unsigned)flag;
    __syncthreads();
    for (int off = 1; off < SCAN_BS; off <<= 1) {
        unsigned add = (t >= off) ? sh[t - off] : 0u;
        __syncthreads();
        sh[t] += add;
        __syncthreads();
    }
    unsigned rank = excl + sh[t] - (unsigned)flag;
    int r = (flag && rank < (unsigned)MAX_VOXv) ? (int)rank : -1;
    rank_of[i] = r;
    if (r >= 0) vid_of_rank[r] = i;
    if (vb == NBLK - 1 && t == SCAN_BS - 1) scal[0] = excl + sh[t];
}

__global__ void k_append2(const int* __restrict__ vids, int N,
                          const int* __restrict__ rank_of,
                          unsigned int* __restrict__ appcnt,
                          float* __restrict__ out) {
    int i = blockIdx.x * blockDim.x + threadIdx.x;
    if (i >= N) return;
    int vid = vids[i];
    if (vid < 0) return;
    int r = rank_of[vid];
    if (r < 0) return;
    unsigned s = atomicAdd(&appcnt[r], 1u);
    if (s < (unsigned)SLOT_CAP) {
        int* rowi = reinterpret_cast<int*>(out + (size_t)r * (MAX_PTSv * 8));
        rowi[s] = i;
    }
}

// emit: 4 rows per 256-thread block (r10-P5 verified)
__global__ void k_emit4(const float* __restrict__ pf,
                        const unsigned int* __restrict__ appcnt,
                        const int* __restrict__ vid_of_rank,
                        const unsigned int* __restrict__ scal,
                        float* __restrict__ out) {
    const int t = threadIdx.x;
    const int sub = t >> 6;
    const int lane = t & 63;
    const int r = blockIdx.x * 4 + sub;
    float* out_coord = out + VOX_F;
    float* out_num   = out + VOX_F + COORD_F;
    unsigned K = min(scal[0], (unsigned)MAX_VOXv);
    float* row = out + (size_t)r * (MAX_PTSv * 8);

    __shared__ int sidx[4][64];
    bool isocc = (unsigned)r < K;
    int c = 0;
    if (isocc) c = (int)min(appcnt[r], (unsigned)SLOT_CAP);
    const int* rowi = reinterpret_cast<const int*>(row);
    sidx[sub][lane] = (lane < c) ? rowi[lane] : 0x7fffffff;
    __syncthreads();                       // slot loads drained before rewrite

    if (isocc) {
        int nkeep = c < MAX_PTSv ? c : MAX_PTSv;
        if (lane < c) {
            int my = sidx[sub][lane];
            int pos = 0;
            for (int j = 0; j < c; ++j) pos += (sidx[sub][j] < my) ? 1 : 0;
            if (pos < MAX_PTSv) {
                const float4* src =
                    reinterpret_cast<const float4*>(pf) + (size_t)my * 2;
                float4 a = src[0];
                float4 b = src[1];
                float4* dst = reinterpret_cast<float4*>(row + pos * 8);
                dst[0] = a;
                dst[1] = b;
            }
        }
        if (lane >= nkeep && lane < MAX_PTSv) {
            float4* dst = reinterpret_cast<float4*>(row + lane * 8);
            dst[0] = make_float4(0.f, 0.f, 0.f, 0.f);
            dst[1] = make_float4(0.f, 0.f, 0.f, 0.f);
        }
        if (lane == 0) {
            int vid = vid_of_rank[r];
            int vx = vid % NXv;
            int vy = (vid / NXv) % NYv;
            int vz = vid / (NXv * NYv);
            out_coord[(size_t)r * 3 + 0] = (float)vz;
            out_coord[(size_t)r * 3 + 1] = (float)vy;
            out_coord[(size_t)r * 3 + 2] = (float)vx;
            out_num[r] = (float)nkeep;
        }
    } else {
        reinterpret_cast<float4*>(row)[lane] = make_float4(0.f, 0.f, 0.f, 0.f);
        if (lane == 0) {
            out_coord[(size_t)r * 3 + 0] = 0.f;
            out_coord[(size_t)r * 3 + 1] = 0.f;
            out_coord[(size_t)r * 3 + 2] = 0.f;
            out_num[r] = 0.f;
        }
    }
}

// ---------- fallback path (r6 proven, 7 kernels) ----------

__global__ void k_zero(unsigned int* p, int n) {
    int i = blockIdx.x * blockDim.x + threadIdx.x;
    int stride = gridDim.x * blockDim.x;
    for (; i < n; i += stride) p[i] = 0u;
}

__global__ void k_count(const float* __restrict__ pf, int N,
                        unsigned int* __restrict__ counts) {
    int i = blockIdx.x * blockDim.x + threadIdx.x;
    if (i >= N) return;
    float4 v = reinterpret_cast<const float4*>(pf)[(size_t)i * 2];
    int vid = voxel_id(v.x, v.y, v.z);
    if (vid >= 0) atomicAdd(&counts[vid], 1u);
}

__global__ void k_blocksum(const unsigned int* __restrict__ counts,
                           unsigned int* __restrict__ bsums) {
    int i = blockIdx.x * SCAN_BS + threadIdx.x;
    int flag = (counts[i] != 0u) ? 1 : 0;
    unsigned long long b = __ballot(flag);
    __shared__ unsigned int wsum[SCAN_BS / 64];
    if ((threadIdx.x & 63) == 0) wsum[threadIdx.x >> 6] = (unsigned)__popcll(b);
    __syncthreads();
    if (threadIdx.x == 0) {
        unsigned s = 0;
        for (int w = 0; w < SCAN_BS / 64; ++w) s += wsum[w];
        bsums[blockIdx.x] = s;
    }
}

__global__ void k_scan_bsums(unsigned int* __restrict__ bsums,
                             unsigned int* __restrict__ scal) {
    __shared__ unsigned int sh[1024];
    int t = threadIdx.x;
    unsigned v = (t < NBLK) ? bsums[t] : 0u;
    sh[t] = v;
    __syncthreads();
    for (int off = 1; off < 1024; off <<= 1) {
        unsigned add = (t >= off) ? sh[t - off] : 0u;
        __syncthreads();
        sh[t] += add;
        __syncthreads();
    }
    if (t < NBLK) bsums[t] = sh[t] - v;
    if (t == NBLK - 1) scal[0] = sh[t];
}

__global__ void k_ranks(const unsigned int* __restrict__ counts,
                        const unsigned int* __restrict__ bsums,
                        int* __restrict__ rank_of, int* __restrict__ vid_of_rank) {
    int i = blockIdx.x * SCAN_BS + threadIdx.x;
    int t = threadIdx.x;
    int flag = (counts[i] != 0u) ? 1 : 0;
    __shared__ unsigned int sh[SCAN_BS];
    sh[t] = (unsigned)flag;
    __syncthreads();
    for (int off = 1; off < SCAN_BS; off <<= 1) {
        unsigned add = (t >= off) ? sh[t - off] : 0u;
        __syncthreads();
        sh[t] += add;
        __syncthreads();
    }
    unsigned rank = bsums[blockIdx.x] + sh[t] - (unsigned)flag;
    int r = (flag && rank < (unsigned)MAX_VOXv) ? (int)rank : -1;
    rank_of[i] = r;
    if (r >= 0) vid_of_rank[r] = i;
}

__global__ void k_append(const float* __restrict__ pf, int N,
                         const int* __restrict__ rank_of,
                         unsigned int* __restrict__ appcnt,
                         float* __restrict__ out) {
    int i = blockIdx.x * blockDim.x + threadIdx.x;
    if (i >= N) return;
    float4 v = reinterpret_cast<const float4*>(pf)[(size_t)i * 2];
    int vid = voxel_id(v.x, v.y, v.z);
    if (vid < 0) return;
    int r = rank_of[vid];
    if (r < 0) return;
    unsigned s = atomicAdd(&appcnt[r], 1u);
    if (s < (unsigned)SLOT_CAP) {
        int* rowi = reinterpret_cast<int*>(out + (size_t)r * (MAX_PTSv * 8));
        rowi[s] = i;
    }
}

__global__ void k_emit(const float* __restrict__ pf,
                       const unsigned int* __restrict__ appcnt,
                       const int* __restrict__ vid_of_rank,
                       const unsigned int* __restrict__ scal,
                       float* __restrict__ out) {
    int r = blockIdx.x;
    int t = threadIdx.x;
    float* row       = out + (size_t)r * (MAX_PTSv * 8);
    float* out_coord = out + VOX_F;
    float* out_num   = out + VOX_F + COORD_F;
    unsigned K = min(scal[0], (unsigned)MAX_VOXv);

    if ((unsigned)r >= K) {
        reinterpret_cast<float4*>(row)[t] = make_float4(0.f, 0.f, 0.f, 0.f);
        if (t == 0) {
            out_coord[(size_t)r * 3 + 0] = 0.f;
            out_coord[(size_t)r * 3 + 1] = 0.f;
            out_coord[(size_t)r * 3 + 2] = 0.f;
            out_num[r] = 0.f;
        }
        return;
    }

    __shared__ int sidx[SLOT_CAP];
    int c = (int)min(appcnt[r], (unsigned)SLOT_CAP);
    const int* rowi = reinterpret_cast<const int*>(row);
    sidx[t] = (t < c) ? rowi[t] : 0x7fffffff;
    __syncthreads();
    int nkeep = c < MAX_PTSv ? c : MAX_PTSv;

    if (t < c) {
        int my = sidx[t];
        int pos = 0;
        for (int j = 0; j < c; ++j) pos += (sidx[j] < my) ? 1 : 0;
        if (pos < MAX_PTSv) {
            const float4* src = reinterpret_cast<const float4*>(pf) + (size_t)my * 2;
            float4 a = src[0];
            float4 b = src[1];
            float4* dst = reinterpret_cast<float4*>(row + pos * 8);
            dst[0] = a;
            dst[1] = b;
        }
    }
    if (t >= nkeep && t < MAX_PTSv) {
        float4* dst = reinterpret_cast<float4*>(row + t * 8);
        dst[0] = make_float4(0.f, 0.f, 0.f, 0.f);
        dst[1] = make_float4(0.f, 0.f, 0.f, 0.f);
    }
    if (t == 0) {
        int vid = vid_of_rank[r];
        int vx = vid % NXv;
        int vy = (vid / NXv) % NYv;
        int vz = vid / (NXv * NYv);
        out_coord[(size_t)r * 3 + 0] = (float)vz;
        out_coord[(size_t)r * 3 + 1] = (float)vy;
        out_coord[(size_t)r * 3 + 2] = (float)vx;
        out_num[r] = (float)nkeep;
    }
}

extern "C" void kernel_launch(void* const* d_in, const int* in_sizes, int n_in,
                              void* d_out, int out_size, void* d_ws, size_t ws_size,
                              hipStream_t stream) {
    const float* pf = (const float*)d_in[0];
    const int N = in_sizes[0] / 8;
    float* out = (float*)d_out;

    // fast-path ws layout (bytes), zero-region first (memset node):
    //   [occ u8 215040][appcnt u32 160000][scal 64]            = 375104 zeroed
    //   [bsums 4096][rank_of i32 NVOX][vid_of_rank i32 MAX_VOX][vids i32 N]
    const size_t OCC_B  = 215040;
    const size_t APP_B  = (size_t)MAX_VOXv * 4;   // 160000
    const size_t SCAL_B = 64;
    const size_t ZERO_B = OCC_B + APP_B + SCAL_B; // 375104
    const size_t BS_B   = 4096;
    const size_t RANK_B = (size_t)NVOX * 4;       // 857088
    const size_t VOR_B  = (size_t)MAX_VOXv * 4;   // 160000
    const size_t NEED   = ZERO_B + BS_B + RANK_B + VOR_B + (size_t)N * 4;

    char* wsb = (char*)d_ws;
    unsigned char* occ        = (unsigned char*)wsb;
    unsigned int* appcnt      = (unsigned int*)(wsb + OCC_B);
    unsigned int* scal        = (unsigned int*)(wsb + OCC_B + APP_B);
    unsigned int* bsums       = (unsigned int*)(wsb + ZERO_B);
    int*          rank_of     = (int*)(wsb + ZERO_B + BS_B);
    int*          vid_of_rank = (int*)(wsb + ZERO_B + BS_B + RANK_B);
    int*          vids        = (int*)(wsb + ZERO_B + BS_B + RANK_B + VOR_B);

    if (ws_size >= NEED) {
        hipMemsetAsync(d_ws, 0, ZERO_B, stream);
        k_prep<<<(N + 255) / 256, 256, 0, stream>>>(pf, N, vids, occ);
        k_blocksum2<<<NBLK, SCAN_BS, 0, stream>>>(occ, bsums);
        k_ranks3<<<NBLK, SCAN_BS, 0, stream>>>(occ, bsums, scal, rank_of, vid_of_rank);
        k_append2<<<(N + 255) / 256, 256, 0, stream>>>(vids, N, rank_of, appcnt, out);
        k_emit4<<<MAX_VOXv / 4, SCAN_BS, 0, stream>>>(pf, appcnt, vid_of_rank, scal, out);
        return;
    }

    // fallback: r6 proven layout/path (~2.04 MB)
    unsigned int* wsp          = (unsigned int*)d_ws;
    unsigned int* counts_f     = wsp;
    unsigned int* appcnt_f     = counts_f + NVOX;
    unsigned int* bsums_f      = appcnt_f + MAX_VOXv;
    unsigned int* scal_f       = bsums_f + 1024;
    int*          rank_of_f    = (int*)(scal_f + 4);
    int*          vid_of_rk_f  = rank_of_f + NVOX;

    const int n_zero = NVOX + MAX_VOXv + 1024 + 4;
    k_zero<<<512, 256, 0, stream>>>(wsp, n_zero);
    k_count<<<(N + 255) / 256, 256, 0, stream>>>(pf, N, counts_f);
    k_blocksum<<<NBLK, SCAN_BS, 0, stream>>>(counts_f, bsums_f);
    k_scan_bsums<<<1, 1024, 0, stream>>>(bsums_f, scal_f);
    k_ranks<<<NBLK, SCAN_BS, 0, stream>>>(counts_f, bsums_f, rank_of_f, vid_of_rk_f);
    k_append<<<(N + 255) / 256, 256, 0, stream>>>(pf, N, rank_of_f, appcnt_f, out);
    k_emit<<<MAX_VOXv, 64, 0, stream>>>(pf, appcnt_f, vid_of_rk_f, scal_f, out);
}